// Round 4
// baseline (90.507 us; speedup 1.0000x reference)
//
#include <hip/hip_runtime.h>
#include <hip/hip_bf16.h>
#include <math.h>

#define NN 55
#define KK 8192
#define OO 8192

using bf16x8 = __attribute__((ext_vector_type(8))) __bf16;
using f32x4  = __attribute__((ext_vector_type(4))) float;

__device__ inline bf16x8 cvt8(f32x4 lo, f32x4 hi) {
    bf16x8 v;
    v[0] = (__bf16)lo[0]; v[1] = (__bf16)lo[1];
    v[2] = (__bf16)lo[2]; v[3] = (__bf16)lo[3];
    v[4] = (__bf16)hi[0]; v[5] = (__bf16)hi[1];
    v[6] = (__bf16)hi[2]; v[7] = (__bf16)hi[3];
    return v;
}

// Kernel 1: x [55,8192] f32 -> xb [64,8192] bf16, rows 55..63 zeroed.
__global__ __launch_bounds__(256)
void cvt_x(const float* __restrict__ xg, __bf16* __restrict__ xb) {
    const int idx = blockIdx.x * 256 + threadIdx.x;
    const int row = idx >> 10;
    const int c8  = (idx & 1023) * 8;
    bf16x8 v = {};
    if (row < NN) {
        const float* p = xg + (size_t)row * KK + c8;
        v = cvt8(*(const f32x4*)p, *(const f32x4*)(p + 4));
    }
    *(bf16x8*)(xb + (size_t)row * KK + c8) = v;
}

__device__ inline void gll16(const float* src, float* dstLds) {
    __builtin_amdgcn_global_load_lds(
        (const __attribute__((address_space(1))) void*)src,
        (__attribute__((address_space(3))) void*)dstLds, 16, 0, 0);
}

#define WAITVM(N) asm volatile("s_waitcnt vmcnt(" #N ")" ::: "memory")
#define BAR() __builtin_amdgcn_s_barrier()

// Kernel 2: out = elu(x @ W^T + b).
// 512 blocks x 512 threads (8 waves), o-tile 16 W-rows per block -> 64KB LDS
// -> 2 blocks/CU (16 waves/CU) so the two blocks' barrier phases interleave.
// K in 32 stages of 256. W staged via global_load_lds (1KB contiguous row-
// chunks, pre-swizzled source / XOR-swizzled ds_read). 4-deep multi-buffer,
// counted vmcnt(12) (3 windows x 6 VMEM in flight), raw barriers. Wave w
// computes k-slice [w*32, w*32+32) of each stage; A register-prefetched
// 4-deep from L2-resident xb. Cross-wave f32 reduce in LDS at the end.
__global__ __launch_bounds__(512, 4)
void gat_gemm_elu4(const __bf16* __restrict__ xb,
                   const float* __restrict__ wg,
                   const float* __restrict__ bg,
                   float* __restrict__ outg) {
    __shared__ float Wbuf[4 * 4096];   // 64 KiB: 4 bufs x (16 rows x 256 f32)

    const int tid  = threadIdx.x;
    const int lane = tid & 63;
    const int w    = tid >> 6;
    const int r    = lane & 15;
    const int q    = lane >> 4;
    const int obase = blockIdx.x * 16;

    // Wave stages rows lr = 2w, 2w+1. LDS chunk c holds global chunk c^(lr&7).
    const float* wsrc[2];
#pragma unroll
    for (int j = 0; j < 2; ++j) {
        const int lr = w * 2 + j;
        wsrc[j] = wg + (size_t)(obase + lr) * KK + ((lane ^ (lr & 7)) << 2);
    }
    const __bf16* abase = xb + (size_t)r * KK + w * 32 + q * 8;

    const int sw  = (r & 7) << 4;
    const int kx0 = (w * 128 + q * 32) ^ sw;
    const int kx1 = (w * 128 + q * 32 + 16) ^ sw;

    f32x4 acc[4] = {};
    bf16x8 A0[4], A1[4], A2[4], A3[4];

#define STAGE_W(BUF, STG) do {                                              \
    const int kb_ = (STG) * 256;                                            \
    _Pragma("unroll")                                                       \
    for (int j = 0; j < 2; ++j) {                                           \
        gll16(wsrc[j] + kb_, &Wbuf[(BUF) * 4096 + (w * 2 + j) * 256]);      \
    } } while (0)

#define LOAD_A(SLOT, STG) do {                                              \
    const __bf16* a_ = abase + (size_t)(STG) * 256;                         \
    SLOT[0] = *(const bf16x8*)(a_);                                         \
    SLOT[1] = *(const bf16x8*)(a_ + (size_t)16 * KK);                       \
    SLOT[2] = *(const bf16x8*)(a_ + (size_t)32 * KK);                       \
    SLOT[3] = *(const bf16x8*)(a_ + (size_t)48 * KK); } while (0)

#define COMPUTE(BUF, AS) do {                                               \
    const char* wb_ = (const char*)&Wbuf[(BUF) * 4096];                     \
    const f32x4 lo0 = *(const f32x4*)(wb_ + r * 1024 + kx0);                \
    const f32x4 hi0 = *(const f32x4*)(wb_ + r * 1024 + kx1);                \
    const bf16x8 b0 = cvt8(lo0, hi0);                                       \
    acc[0] = __builtin_amdgcn_mfma_f32_16x16x32_bf16(AS[0], b0, acc[0], 0, 0, 0); \
    acc[1] = __builtin_amdgcn_mfma_f32_16x16x32_bf16(AS[1], b0, acc[1], 0, 0, 0); \
    acc[2] = __builtin_amdgcn_mfma_f32_16x16x32_bf16(AS[2], b0, acc[2], 0, 0, 0); \
    acc[3] = __builtin_amdgcn_mfma_f32_16x16x32_bf16(AS[3], b0, acc[3], 0, 0, 0); \
    } while (0)

    // prologue: 3 stage-windows in flight (6 VMEM each)
    STAGE_W(0, 0); LOAD_A(A0, 0);
    STAGE_W(1, 1); LOAD_A(A1, 1);
    STAGE_W(2, 2); LOAD_A(A2, 2);

    int s = 0;
#pragma unroll 1
    for (int su = 0; su < 7; ++su) {
        WAITVM(12); BAR(); STAGE_W(3, s + 3); LOAD_A(A3, s + 3); COMPUTE(0, A0);
        WAITVM(12); BAR(); STAGE_W(0, s + 4); LOAD_A(A0, s + 4); COMPUTE(1, A1);
        WAITVM(12); BAR(); STAGE_W(1, s + 5); LOAD_A(A1, s + 5); COMPUTE(2, A2);
        WAITVM(12); BAR(); STAGE_W(2, s + 6); LOAD_A(A2, s + 6); COMPUTE(3, A3);
        s += 4;
    }
    // tail: s = 28..31
    WAITVM(12); BAR(); STAGE_W(3, 31); LOAD_A(A3, 31); COMPUTE(0, A0);
    WAITVM(12); BAR(); COMPUTE(1, A1);
    WAITVM(6);  BAR(); COMPUTE(2, A2);
    WAITVM(0);  BAR(); COMPUTE(3, A3);

    // cross-wave reduce: alias bufs 0-1 (32KB); all waves are past COMPUTE(1)
    // (two barriers ago), and buf3 reads are disjoint from this region.
    float* red = Wbuf;
#pragma unroll
    for (int mt = 0; mt < 4; ++mt) {
#pragma unroll
        for (int e = 0; e < 4; ++e) {
            const int row = mt * 16 + q * 4 + e;
            red[w * 1024 + row * 16 + r] = acc[mt][e];
        }
    }
    __syncthreads();

    for (int i = tid; i < 1024; i += 512) {
        float ssum = 0.f;
#pragma unroll
        for (int ww = 0; ww < 8; ++ww) ssum += red[ww * 1024 + i];
        const int row = i >> 4;
        const int col = i & 15;
        const float v = ssum + bg[obase + col];
        const float res = (v > 0.f) ? v : expm1f(v);
        if (row < NN) outg[(size_t)row * OO + obase + col] = res;
    }
#undef STAGE_W
#undef LOAD_A
#undef COMPUTE
}

extern "C" void kernel_launch(void* const* d_in, const int* in_sizes, int n_in,
                              void* d_out, int out_size, void* d_ws, size_t ws_size,
                              hipStream_t stream) {
    const float* x  = (const float*)d_in[0];
    const float* W1 = (const float*)d_in[3];
    const float* b1 = (const float*)d_in[4];
    float* out = (float*)d_out;
    __bf16* xb = (__bf16*)d_ws;   // 64*8192*2 = 1 MB

    cvt_x<<<dim3(256), dim3(256), 0, stream>>>(x, xb);
    gat_gemm_elu4<<<dim3(OO / 16), dim3(512), 0, stream>>>(xb, W1, b1, out);
}

// Round 5
// 89.399 us; speedup vs baseline: 1.0124x; 1.0124x over previous
//
#include <hip/hip_runtime.h>
#include <hip/hip_bf16.h>
#include <math.h>

#define NN 55
#define KK 8192
#define OO 8192

using bf16x8 = __attribute__((ext_vector_type(8))) __bf16;
using f32x4  = __attribute__((ext_vector_type(4))) float;

__device__ inline bf16x8 cvt8(f32x4 lo, f32x4 hi) {
    bf16x8 v;
    v[0] = (__bf16)lo[0]; v[1] = (__bf16)lo[1];
    v[2] = (__bf16)lo[2]; v[3] = (__bf16)lo[3];
    v[4] = (__bf16)hi[0]; v[5] = (__bf16)hi[1];
    v[6] = (__bf16)hi[2]; v[7] = (__bf16)hi[3];
    return v;
}

// Kernel 1: x [55,8192] f32 -> xb [64,8192] bf16, rows 55..63 zeroed.
__global__ __launch_bounds__(256)
void cvt_x(const float* __restrict__ xg, __bf16* __restrict__ xb) {
    const int idx = blockIdx.x * 256 + threadIdx.x;
    const int row = idx >> 10;
    const int c8  = (idx & 1023) * 8;
    bf16x8 v = {};
    if (row < NN) {
        const float* p = xg + (size_t)row * KK + c8;
        v = cvt8(*(const f32x4*)p, *(const f32x4*)(p + 4));
    }
    *(bf16x8*)(xb + (size_t)row * KK + c8) = v;
}

__device__ inline void gll16(const float* src, float* dstLds) {
    __builtin_amdgcn_global_load_lds(
        (const __attribute__((address_space(1))) void*)src,
        (__attribute__((address_space(3))) void*)dstLds, 16, 0, 0);
}

#define WAITVM(N) asm volatile("s_waitcnt vmcnt(" #N ")" ::: "memory")
#define BAR() __builtin_amdgcn_s_barrier()

// Kernel 2: out = elu(x @ W^T + b).
// 512 blocks x 512 threads (8 waves), o-tile 16 W-rows, 1 block/CU (128KB LDS,
// launch_bounds(512,2) -> VGPR cap 256, no spill). K in 16 stages of 512:
// each W row read as a 2KB contiguous burst per stage (2 gll16 back-to-back)
// -- 2x the DRAM burst locality of R3. 4-deep LDS multi-buffer, single
// barrier per line, counted vmcnt (steady 16). A (bf16 xb, L2-resident)
// register-prefetched 2 stages ahead in 2 slots; compute-first line ordering
// so slot parity works: line s = [WAITVM;BAR; COMPUTE(s); LOAD_A(s+2);
// STAGE_W(s+3)]. Queue/line = 8 A-loads + 4 gll16 = 12 ops; at line s the
// ops newer than A(s) are W(s+1),A(s+1),W(s+2) = 16 -> vmcnt(16).
__global__ __launch_bounds__(512, 2)
void gat_gemm_elu5(const __bf16* __restrict__ xb,
                   const float* __restrict__ wg,
                   const float* __restrict__ bg,
                   float* __restrict__ outg) {
    __shared__ float Wbuf[4 * 8192];   // 128 KiB: 4 bufs x (16 rows x 512 f32)

    const int tid  = threadIdx.x;
    const int lane = tid & 63;
    const int w    = tid >> 6;
    const int r    = lane & 15;
    const int q    = lane >> 4;
    const int obase = blockIdx.x * 16;

    // Wave stages rows lr = 2w, 2w+1. LDS 16B-chunk c of a row holds global
    // chunk c^(lr&7) (involution within 128B windows, within each KB).
    const float* wsrc[2];
#pragma unroll
    for (int j = 0; j < 2; ++j) {
        const int lr = w * 2 + j;
        wsrc[j] = wg + (size_t)(obase + lr) * KK + ((lane ^ (lr & 7)) << 2);
    }
    const __bf16* abase = xb + (size_t)r * KK + w * 64 + q * 8;

    const int sw      = (r & 7) << 4;
    const int kxlo    = (q * 32) ^ sw;        // swizzled low-16B offset
    const int kxhi    = (q * 32 + 16) ^ sw;   // swizzled high-16B offset
    const int rowbase = r * 2048 + w * 256;   // byte offset of this wave's k-slice

    f32x4 acc[4] = {};
    bf16x8 A0[8], A1[8];   // [mt*2+ks], 2-stage ping-pong

#define STAGE_W(BUF, STG) do {                                               \
    _Pragma("unroll")                                                        \
    for (int j = 0; j < 2; ++j) {                                            \
        _Pragma("unroll")                                                    \
        for (int h = 0; h < 2; ++h) {                                        \
            gll16(wsrc[j] + (STG) * 512 + h * 256,                           \
                  &Wbuf[(BUF) * 8192 + (w * 2 + j) * 512 + h * 256]);        \
        }                                                                    \
    } } while (0)

#define LOAD_A(SLOT, STG) do {                                               \
    const __bf16* a_ = abase + (size_t)(STG) * 512;                          \
    _Pragma("unroll")                                                        \
    for (int mt = 0; mt < 4; ++mt) {                                         \
        _Pragma("unroll")                                                    \
        for (int ks = 0; ks < 2; ++ks) {                                     \
            SLOT[mt * 2 + ks] =                                              \
                *(const bf16x8*)(a_ + (size_t)mt * 16 * KK + ks * 32);       \
        }                                                                    \
    } } while (0)

#define COMPUTE(BUF, AS) do {                                                \
    const char* wb_ = (const char*)&Wbuf[(BUF) * 8192] + rowbase;            \
    _Pragma("unroll")                                                        \
    for (int ks = 0; ks < 2; ++ks) {                                         \
        const f32x4 lo = *(const f32x4*)(wb_ + ks * 128 + kxlo);             \
        const f32x4 hi = *(const f32x4*)(wb_ + ks * 128 + kxhi);             \
        const bf16x8 b0 = cvt8(lo, hi);                                      \
        acc[0] = __builtin_amdgcn_mfma_f32_16x16x32_bf16(AS[0 * 2 + ks], b0, acc[0], 0, 0, 0); \
        acc[1] = __builtin_amdgcn_mfma_f32_16x16x32_bf16(AS[1 * 2 + ks], b0, acc[1], 0, 0, 0); \
        acc[2] = __builtin_amdgcn_mfma_f32_16x16x32_bf16(AS[2 * 2 + ks], b0, acc[2], 0, 0, 0); \
        acc[3] = __builtin_amdgcn_mfma_f32_16x16x32_bf16(AS[3 * 2 + ks], b0, acc[3], 0, 0, 0); \
    } } while (0)

    // prologue, issue order fixes the vmcnt ages: W0, A0, W1, A1, W2
    STAGE_W(0, 0);
    LOAD_A(A0, 0);
    STAGE_W(1, 1);
    LOAD_A(A1, 1);
    STAGE_W(2, 2);

    // main: lines s = 0..11 (unroll by 4 -> static buf indices)
#pragma unroll 1
    for (int su = 0; su < 3; ++su) {
        const int s = su * 4;
        WAITVM(16); BAR(); COMPUTE(0, A0); LOAD_A(A0, s + 2); STAGE_W(3, s + 3);
        WAITVM(16); BAR(); COMPUTE(1, A1); LOAD_A(A1, s + 3); STAGE_W(0, s + 4);
        WAITVM(16); BAR(); COMPUTE(2, A0); LOAD_A(A0, s + 4); STAGE_W(1, s + 5);
        WAITVM(16); BAR(); COMPUTE(3, A1); LOAD_A(A1, s + 5); STAGE_W(2, s + 6);
    }
    // line 12 (full), then drain
    WAITVM(16); BAR(); COMPUTE(0, A0); LOAD_A(A0, 14); STAGE_W(3, 15);
    WAITVM(16); BAR(); COMPUTE(1, A1); LOAD_A(A1, 15);
    WAITVM(12); BAR(); COMPUTE(2, A0);
    WAITVM(0);  BAR(); COMPUTE(3, A1);

    // cross-wave reduce in bufs 0-1 region (laggards only touch buf 3)
    float* red = Wbuf;
#pragma unroll
    for (int mt = 0; mt < 4; ++mt) {
#pragma unroll
        for (int e = 0; e < 4; ++e) {
            const int row = mt * 16 + q * 4 + e;
            red[w * 1024 + row * 16 + r] = acc[mt][e];
        }
    }
    __syncthreads();

    for (int i = tid; i < 1024; i += 512) {
        float ssum = 0.f;
#pragma unroll
        for (int ww = 0; ww < 8; ++ww) ssum += red[ww * 1024 + i];
        const int row = i >> 4;
        const int col = i & 15;
        const float v = ssum + bg[obase + col];
        const float res = (v > 0.f) ? v : expm1f(v);
        if (row < NN) outg[(size_t)row * OO + obase + col] = res;
    }
#undef STAGE_W
#undef LOAD_A
#undef COMPUTE
}

extern "C" void kernel_launch(void* const* d_in, const int* in_sizes, int n_in,
                              void* d_out, int out_size, void* d_ws, size_t ws_size,
                              hipStream_t stream) {
    const float* x  = (const float*)d_in[0];
    const float* W1 = (const float*)d_in[3];
    const float* b1 = (const float*)d_in[4];
    float* out = (float*)d_out;
    __bf16* xb = (__bf16*)d_ws;   // 64*8192*2 = 1 MB

    cvt_x<<<dim3(256), dim3(256), 0, stream>>>(x, xb);
    gat_gemm_elu5<<<dim3(OO / 16), dim3(512), 0, stream>>>(xb, W1, b1, out);
}

// Round 6
// 68.526 us; speedup vs baseline: 1.3208x; 1.3046x over previous
//
#include <hip/hip_runtime.h>
#include <hip/hip_bf16.h>
#include <math.h>

#define NN 55
#define KK 8192
#define OO 8192

using bf16x8 = __attribute__((ext_vector_type(8))) __bf16;
using f32x4  = __attribute__((ext_vector_type(4))) float;

__device__ inline bf16x8 cvt8(f32x4 lo, f32x4 hi) {
    bf16x8 v;
    v[0] = (__bf16)lo[0]; v[1] = (__bf16)lo[1];
    v[2] = (__bf16)lo[2]; v[3] = (__bf16)lo[3];
    v[4] = (__bf16)hi[0]; v[5] = (__bf16)hi[1];
    v[6] = (__bf16)hi[2]; v[7] = (__bf16)hi[3];
    return v;
}

// Kernel 1: x [55,8192] f32 -> xb [64,8192] bf16, rows 55..63 zeroed.
__global__ __launch_bounds__(256)
void cvt_x(const float* __restrict__ xg, __bf16* __restrict__ xb) {
    const int idx = blockIdx.x * 256 + threadIdx.x;
    const int row = idx >> 10;
    const int c8  = (idx & 1023) * 8;
    bf16x8 v = {};
    if (row < NN) {
        const float* p = xg + (size_t)row * KK + c8;
        v = cvt8(*(const f32x4*)p, *(const f32x4*)(p + 4));
    }
    *(bf16x8*)(xb + (size_t)row * KK + c8) = v;
}

// W staging: non-temporal (aux=2) -- W is read-once, keep it out of L2/L3 reuse.
__device__ inline void gll16nt(const float* src, float* dstLds) {
    __builtin_amdgcn_global_load_lds(
        (const __attribute__((address_space(1))) void*)src,
        (__attribute__((address_space(3))) void*)dstLds, 16, 0, 2);
}

#define WAITVM(N) asm volatile("s_waitcnt vmcnt(" #N ")" ::: "memory")
#define BAR() __builtin_amdgcn_s_barrier()

// Kernel 2: out = elu(x @ W^T + b).   R3 structure + depth-3 + NT.
// 256 blocks x 512 threads (8 waves), o-tile 32 W-rows, 1 block/CU.
// K in 32 stages of 256 (one line each: WAITVM(24); BAR; STAGE_W(s+4);
// LOAD_A(s+4); COMPUTE(s)). 5 LDS bufs x 32KB = 160KB (full pool) ->
// 3 stages in flight. Window = 8 VMEM/line (4 gll16 + 4 A) -> steady
// vmcnt(24) = 3 lines. Wave w computes k-slice [w*32,w*32+32) per stage;
// A register-prefetched 4 stages ahead in 5 named slots (static indexing).
__global__ __launch_bounds__(512, 2)
void gat_gemm_elu6(const __bf16* __restrict__ xb,
                   const float* __restrict__ wg,
                   const float* __restrict__ bg,
                   float* __restrict__ outg) {
    __shared__ float Wbuf[5 * 8192];   // 160 KiB: 5 bufs x (32 rows x 256 f32)

    const int tid  = threadIdx.x;
    const int lane = tid & 63;
    const int w    = tid >> 6;
    const int r    = lane & 15;
    const int q    = lane >> 4;
    const int w4   = w * 4;
    const int obase = blockIdx.x * 32;

    // Wave stages rows lr = 4w..4w+3. LDS 16B-chunk c holds global chunk
    // c^(lr&7) (involution within each row's 1KB).
    const float* wsrc[4];
#pragma unroll
    for (int j = 0; j < 4; ++j) {
        const int lr = w4 + j;
        wsrc[j] = wg + (size_t)(obase + lr) * KK + ((lane ^ (lr & 7)) << 2);
    }
    const __bf16* abase = xb + (size_t)r * KK + w * 32 + q * 8;

    const int sw  = (r & 7) << 4;
    const int kx0 = (w * 128 + q * 32) ^ sw;
    const int kx1 = (w * 128 + q * 32 + 16) ^ sw;

    f32x4 acc0[4] = {};
    f32x4 acc1[4] = {};
    bf16x8 A0[4], A1[4], A2[4], A3[4], A4[4];

#define STAGE_W(BUF, STG) do {                                              \
    const int kb_ = (STG) * 256;                                            \
    _Pragma("unroll")                                                       \
    for (int j = 0; j < 4; ++j) {                                           \
        gll16nt(wsrc[j] + kb_, &Wbuf[(BUF) * 8192 + (w4 + j) * 256]);       \
    } } while (0)

#define LOAD_A(SLOT, STG) do {                                              \
    const __bf16* a_ = abase + (size_t)(STG) * 256;                         \
    SLOT[0] = *(const bf16x8*)(a_);                                         \
    SLOT[1] = *(const bf16x8*)(a_ + (size_t)16 * KK);                       \
    SLOT[2] = *(const bf16x8*)(a_ + (size_t)32 * KK);                       \
    SLOT[3] = *(const bf16x8*)(a_ + (size_t)48 * KK); } while (0)

#define COMPUTE(BUF, AS) do {                                               \
    const char* wb_ = (const char*)&Wbuf[(BUF) * 8192];                     \
    const f32x4 lo0 = *(const f32x4*)(wb_ + r * 1024 + kx0);                \
    const f32x4 hi0 = *(const f32x4*)(wb_ + r * 1024 + kx1);                \
    const f32x4 lo1 = *(const f32x4*)(wb_ + (16 + r) * 1024 + kx0);         \
    const f32x4 hi1 = *(const f32x4*)(wb_ + (16 + r) * 1024 + kx1);         \
    const bf16x8 b0 = cvt8(lo0, hi0);                                       \
    const bf16x8 b1 = cvt8(lo1, hi1);                                       \
    acc0[0] = __builtin_amdgcn_mfma_f32_16x16x32_bf16(AS[0], b0, acc0[0], 0, 0, 0); \
    acc1[0] = __builtin_amdgcn_mfma_f32_16x16x32_bf16(AS[0], b1, acc1[0], 0, 0, 0); \
    acc0[1] = __builtin_amdgcn_mfma_f32_16x16x32_bf16(AS[1], b0, acc0[1], 0, 0, 0); \
    acc1[1] = __builtin_amdgcn_mfma_f32_16x16x32_bf16(AS[1], b1, acc1[1], 0, 0, 0); \
    acc0[2] = __builtin_amdgcn_mfma_f32_16x16x32_bf16(AS[2], b0, acc0[2], 0, 0, 0); \
    acc1[2] = __builtin_amdgcn_mfma_f32_16x16x32_bf16(AS[2], b1, acc1[2], 0, 0, 0); \
    acc0[3] = __builtin_amdgcn_mfma_f32_16x16x32_bf16(AS[3], b0, acc0[3], 0, 0, 0); \
    acc1[3] = __builtin_amdgcn_mfma_f32_16x16x32_bf16(AS[3], b1, acc1[3], 0, 0, 0); \
    } while (0)

    // prologue: 4 stage-windows in flight ([W,A] x stages 0..3, 32 ops)
    STAGE_W(0, 0); LOAD_A(A0, 0);
    STAGE_W(1, 1); LOAD_A(A1, 1);
    STAGE_W(2, 2); LOAD_A(A2, 2);
    STAGE_W(3, 3); LOAD_A(A3, 3);

    // main: s = 0..24 in groups of 5 (static buf/slot mod-5 indices)
#pragma unroll 1
    for (int b = 0; b < 25; b += 5) {
        WAITVM(24); BAR(); STAGE_W(4, b + 4); LOAD_A(A4, b + 4); COMPUTE(0, A0);
        WAITVM(24); BAR(); STAGE_W(0, b + 5); LOAD_A(A0, b + 5); COMPUTE(1, A1);
        WAITVM(24); BAR(); STAGE_W(1, b + 6); LOAD_A(A1, b + 6); COMPUTE(2, A2);
        WAITVM(24); BAR(); STAGE_W(2, b + 7); LOAD_A(A2, b + 7); COMPUTE(3, A3);
        WAITVM(24); BAR(); STAGE_W(3, b + 8); LOAD_A(A3, b + 8); COMPUTE(4, A4);
    }
    // s = 25, 26, 27 (last stages 29..31 issued)
    WAITVM(24); BAR(); STAGE_W(4, 29); LOAD_A(A4, 29); COMPUTE(0, A0);
    WAITVM(24); BAR(); STAGE_W(0, 30); LOAD_A(A0, 30); COMPUTE(1, A1);
    WAITVM(24); BAR(); STAGE_W(1, 31); LOAD_A(A1, 31); COMPUTE(2, A2);
    // s = 28..31: drain
    WAITVM(24); BAR(); COMPUTE(3, A3);
    WAITVM(16); BAR(); COMPUTE(4, A4);
    WAITVM(8);  BAR(); COMPUTE(0, A0);
    WAITVM(0);  BAR(); COMPUTE(1, A1);

    // cross-wave reduce in bufs 2-3 (64KB). After the final BAR, laggard
    // waves only read bufs 0/1 (s=30,31); bufs 2/3 last read at s<=28,
    // which every wave completed before the s=29 barrier.
    float* red = &Wbuf[2 * 8192];
#pragma unroll
    for (int mt = 0; mt < 4; ++mt) {
#pragma unroll
        for (int e = 0; e < 4; ++e) {
            const int row = mt * 16 + q * 4 + e;
            red[w * 2048 + row * 32 + r]      = acc0[mt][e];
            red[w * 2048 + row * 32 + 16 + r] = acc1[mt][e];
        }
    }
    __syncthreads();

    for (int i = tid; i < 2048; i += 512) {
        float ssum = 0.f;
#pragma unroll
        for (int ww = 0; ww < 8; ++ww) ssum += red[ww * 2048 + i];
        const int row = i >> 5;
        const int col = i & 31;
        const float v = ssum + bg[obase + col];
        const float res = (v > 0.f) ? v : expm1f(v);
        if (row < NN) outg[(size_t)row * OO + obase + col] = res;
    }
#undef STAGE_W
#undef LOAD_A
#undef COMPUTE
}

extern "C" void kernel_launch(void* const* d_in, const int* in_sizes, int n_in,
                              void* d_out, int out_size, void* d_ws, size_t ws_size,
                              hipStream_t stream) {
    const float* x  = (const float*)d_in[0];
    const float* W1 = (const float*)d_in[3];
    const float* b1 = (const float*)d_in[4];
    float* out = (float*)d_out;
    __bf16* xb = (__bf16*)d_ws;   // 64*8192*2 = 1 MB

    cvt_x<<<dim3(256), dim3(256), 0, stream>>>(x, xb);
    gat_gemm_elu6<<<dim3(OO / 32), dim3(512), 0, stream>>>(xb, W1, b1, out);
}

// Round 7
// 63.293 us; speedup vs baseline: 1.4300x; 1.0827x over previous
//
#include <hip/hip_runtime.h>
#include <hip/hip_bf16.h>
#include <math.h>

#define NN 55
#define KK 8192
#define OO 8192

using bf16x8 = __attribute__((ext_vector_type(8))) __bf16;
using f32x4  = __attribute__((ext_vector_type(4))) float;

__device__ inline bf16x8 cvt8(f32x4 lo, f32x4 hi) {
    bf16x8 v;
    v[0] = (__bf16)lo[0]; v[1] = (__bf16)lo[1];
    v[2] = (__bf16)lo[2]; v[3] = (__bf16)lo[3];
    v[4] = (__bf16)hi[0]; v[5] = (__bf16)hi[1];
    v[6] = (__bf16)hi[2]; v[7] = (__bf16)hi[3];
    return v;
}

// Kernel 1: x [55,8192] f32 -> xb [64,8192] bf16, rows 55..63 zeroed.
__global__ __launch_bounds__(256)
void cvt_x(const float* __restrict__ xg, __bf16* __restrict__ xb) {
    const int idx = blockIdx.x * 256 + threadIdx.x;
    const int row = idx >> 10;
    const int c8  = (idx & 1023) * 8;
    bf16x8 v = {};
    if (row < NN) {
        const float* p = xg + (size_t)row * KK + c8;
        v = cvt8(*(const f32x4*)p, *(const f32x4*)(p + 4));
    }
    *(bf16x8*)(xb + (size_t)row * KK + c8) = v;
}

// W staging: default cache policy (aux=0) -- L3 retention of W across replays
// is worth ~6us (R6 NT experiment); do NOT mark streaming.
__device__ inline void gll16(const float* src, float* dstLds) {
    __builtin_amdgcn_global_load_lds(
        (const __attribute__((address_space(1))) void*)src,
        (__attribute__((address_space(3))) void*)dstLds, 16, 0, 0);
}

#define WAITVM(N) asm volatile("s_waitcnt vmcnt(" #N ")" ::: "memory")
#define BAR() __builtin_amdgcn_s_barrier()

// Kernel 2: out = elu(x @ W^T + b).   R3 structure + depth-3 (no NT).
// 256 blocks x 512 threads (8 waves), o-tile 32 W-rows, 1 block/CU.
// K in 32 stages of 256 (one line each: WAITVM(24); BAR; STAGE_W(s+4);
// LOAD_A(s+4); COMPUTE(s)). 5 LDS bufs x 32KB = 160KB (full pool) ->
// 3 stages fully in flight. Window = 8 VMEM/line (4 gll16 + 4 A) -> steady
// vmcnt(24) = 3 lines. Wave w computes k-slice [w*32,w*32+32) per stage;
// A register-prefetched 4 stages ahead in 5 named slots (static indexing).
__global__ __launch_bounds__(512, 2)
void gat_gemm_elu7(const __bf16* __restrict__ xb,
                   const float* __restrict__ wg,
                   const float* __restrict__ bg,
                   float* __restrict__ outg) {
    __shared__ float Wbuf[5 * 8192];   // 160 KiB: 5 bufs x (32 rows x 256 f32)

    const int tid  = threadIdx.x;
    const int lane = tid & 63;
    const int w    = tid >> 6;
    const int r    = lane & 15;
    const int q    = lane >> 4;
    const int w4   = w * 4;
    const int obase = blockIdx.x * 32;

    // Wave stages rows lr = 4w..4w+3. LDS 16B-chunk c holds global chunk
    // c^(lr&7) (involution within each row's 1KB).
    const float* wsrc[4];
#pragma unroll
    for (int j = 0; j < 4; ++j) {
        const int lr = w4 + j;
        wsrc[j] = wg + (size_t)(obase + lr) * KK + ((lane ^ (lr & 7)) << 2);
    }
    const __bf16* abase = xb + (size_t)r * KK + w * 32 + q * 8;

    const int sw  = (r & 7) << 4;
    const int kx0 = (w * 128 + q * 32) ^ sw;
    const int kx1 = (w * 128 + q * 32 + 16) ^ sw;

    f32x4 acc0[4] = {};
    f32x4 acc1[4] = {};
    bf16x8 A0[4], A1[4], A2[4], A3[4], A4[4];

#define STAGE_W(BUF, STG) do {                                              \
    const int kb_ = (STG) * 256;                                            \
    _Pragma("unroll")                                                       \
    for (int j = 0; j < 4; ++j) {                                           \
        gll16(wsrc[j] + kb_, &Wbuf[(BUF) * 8192 + (w4 + j) * 256]);         \
    } } while (0)

#define LOAD_A(SLOT, STG) do {                                              \
    const __bf16* a_ = abase + (size_t)(STG) * 256;                         \
    SLOT[0] = *(const bf16x8*)(a_);                                         \
    SLOT[1] = *(const bf16x8*)(a_ + (size_t)16 * KK);                       \
    SLOT[2] = *(const bf16x8*)(a_ + (size_t)32 * KK);                       \
    SLOT[3] = *(const bf16x8*)(a_ + (size_t)48 * KK); } while (0)

#define COMPUTE(BUF, AS) do {                                               \
    const char* wb_ = (const char*)&Wbuf[(BUF) * 8192];                     \
    const f32x4 lo0 = *(const f32x4*)(wb_ + r * 1024 + kx0);                \
    const f32x4 hi0 = *(const f32x4*)(wb_ + r * 1024 + kx1);                \
    const f32x4 lo1 = *(const f32x4*)(wb_ + (16 + r) * 1024 + kx0);         \
    const f32x4 hi1 = *(const f32x4*)(wb_ + (16 + r) * 1024 + kx1);         \
    const bf16x8 b0 = cvt8(lo0, hi0);                                       \
    const bf16x8 b1 = cvt8(lo1, hi1);                                      \
    acc0[0] = __builtin_amdgcn_mfma_f32_16x16x32_bf16(AS[0], b0, acc0[0], 0, 0, 0); \
    acc1[0] = __builtin_amdgcn_mfma_f32_16x16x32_bf16(AS[0], b1, acc1[0], 0, 0, 0); \
    acc0[1] = __builtin_amdgcn_mfma_f32_16x16x32_bf16(AS[1], b0, acc0[1], 0, 0, 0); \
    acc1[1] = __builtin_amdgcn_mfma_f32_16x16x32_bf16(AS[1], b1, acc1[1], 0, 0, 0); \
    acc0[2] = __builtin_amdgcn_mfma_f32_16x16x32_bf16(AS[2], b0, acc0[2], 0, 0, 0); \
    acc1[2] = __builtin_amdgcn_mfma_f32_16x16x32_bf16(AS[2], b1, acc1[2], 0, 0, 0); \
    acc0[3] = __builtin_amdgcn_mfma_f32_16x16x32_bf16(AS[3], b0, acc0[3], 0, 0, 0); \
    acc1[3] = __builtin_amdgcn_mfma_f32_16x16x32_bf16(AS[3], b1, acc1[3], 0, 0, 0); \
    } while (0)

    // prologue: 4 stage-windows in flight ([W,A] x stages 0..3, 32 ops)
    STAGE_W(0, 0); LOAD_A(A0, 0);
    STAGE_W(1, 1); LOAD_A(A1, 1);
    STAGE_W(2, 2); LOAD_A(A2, 2);
    STAGE_W(3, 3); LOAD_A(A3, 3);

    // main: s = 0..24 in groups of 5 (static buf/slot mod-5 indices)
#pragma unroll 1
    for (int b = 0; b < 25; b += 5) {
        WAITVM(24); BAR(); STAGE_W(4, b + 4); LOAD_A(A4, b + 4); COMPUTE(0, A0);
        WAITVM(24); BAR(); STAGE_W(0, b + 5); LOAD_A(A0, b + 5); COMPUTE(1, A1);
        WAITVM(24); BAR(); STAGE_W(1, b + 6); LOAD_A(A1, b + 6); COMPUTE(2, A2);
        WAITVM(24); BAR(); STAGE_W(2, b + 7); LOAD_A(A2, b + 7); COMPUTE(3, A3);
        WAITVM(24); BAR(); STAGE_W(3, b + 8); LOAD_A(A3, b + 8); COMPUTE(4, A4);
    }
    // s = 25, 26, 27 (last stages 29..31 issued)
    WAITVM(24); BAR(); STAGE_W(4, 29); LOAD_A(A4, 29); COMPUTE(0, A0);
    WAITVM(24); BAR(); STAGE_W(0, 30); LOAD_A(A0, 30); COMPUTE(1, A1);
    WAITVM(24); BAR(); STAGE_W(1, 31); LOAD_A(A1, 31); COMPUTE(2, A2);
    // s = 28..31: drain
    WAITVM(24); BAR(); COMPUTE(3, A3);
    WAITVM(16); BAR(); COMPUTE(4, A4);
    WAITVM(8);  BAR(); COMPUTE(0, A0);
    WAITVM(0);  BAR(); COMPUTE(1, A1);

    // cross-wave reduce in bufs 2-3 (64KB). After the final BAR, laggard
    // waves only read bufs 0/1 (s=30,31); bufs 2/3 last read at s<=28,
    // which every wave completed before the s=29 barrier.
    float* red = &Wbuf[2 * 8192];
#pragma unroll
    for (int mt = 0; mt < 4; ++mt) {
#pragma unroll
        for (int e = 0; e < 4; ++e) {
            const int row = mt * 16 + q * 4 + e;
            red[w * 2048 + row * 32 + r]      = acc0[mt][e];
            red[w * 2048 + row * 32 + 16 + r] = acc1[mt][e];
        }
    }
    __syncthreads();

    for (int i = tid; i < 2048; i += 512) {
        float ssum = 0.f;
#pragma unroll
        for (int ww = 0; ww < 8; ++ww) ssum += red[ww * 2048 + i];
        const int row = i >> 5;
        const int col = i & 31;
        const float v = ssum + bg[obase + col];
        const float res = (v > 0.f) ? v : expm1f(v);
        if (row < NN) outg[(size_t)row * OO + obase + col] = res;
    }
#undef STAGE_W
#undef LOAD_A
#undef COMPUTE
}

extern "C" void kernel_launch(void* const* d_in, const int* in_sizes, int n_in,
                              void* d_out, int out_size, void* d_ws, size_t ws_size,
                              hipStream_t stream) {
    const float* x  = (const float*)d_in[0];
    const float* W1 = (const float*)d_in[3];
    const float* b1 = (const float*)d_in[4];
    float* out = (float*)d_out;
    __bf16* xb = (__bf16*)d_ws;   // 64*8192*2 = 1 MB

    cvt_x<<<dim3(256), dim3(256), 0, stream>>>(x, xb);
    gat_gemm_elu7<<<dim3(OO / 32), dim3(512), 0, stream>>>(xb, W1, b1, out);
}